// Round 6
// baseline (320.801 us; speedup 1.0000x reference)
//
#include <hip/hip_runtime.h>
#include <hip/hip_bf16.h>

// VoxelGrid: 10M events -> (10, 720, 1280) fp32 grid, bilinear splat in time.
// R1: naive 20M device atomics -> 958 us. R2-R5: bucket sort evolution -> 415.
// R10: polarity split: p3 is LDS-atomic-MESSAGE throughput bound
//   (~3.3 cyc/msg/CU), not latency.
// R11: ONE packed ds_add_u32 per event (16b fixed point, bin-parity words)
//   -> p3 ~116 -> ~40 us. Model CONFIRMED. Total 395 -> 310.
// R12: memoized hist-return j (20M->10M LDS msgs): p2 UNCHANGED; wk/gj in
//   scratch (WRITE 150MB). p2 NOT atomic-count-bound.
// R13: chunked staging (5x8/thr) -> scratch gone (WRITE 52MB, VGPR 36) but
//   p2 108: block-wide barriers SERIALIZE atomic-phase vs store-phase
//   (54us atomics + ~50us mem ~= 108).
// R14: TLP attempt via launch_bounds(1024,8) CONFOUNDED: allocator hit a
//   20-VGPR target and spilled staging back to scratch (WRITE 75MB) ->
//   122us. Lever never engaged.
// R15: TLP via geometry instead of caps: 1024 blocks x 512 threads
//   (4 blocks/CU = 2048 thr, HW cap), NO launch_bounds (R13 shape = 36
//   VGPR fits 4 blocks). CH=2, EPT=10 (fewer barriers). Blocks interleave
//   atomic-phase and store-phase on each CU.

#define NUM_BINS 5
#define DT_OFFSET 1
#define GW 1280
#define GH 720
#define NSLAB (NUM_BINS * 2)   // 10 (bin, polarity) slabs in the OUTPUT
#define NGRP 240               // coarse buckets (y/3)
#define NB2 1024               // phase-2 blocks (4 per CU)
#define TB2 512                // phase-2 block size
#define CH 2                   // chunks per block
#define EPT 10                 // events per thread per chunk
#define ITERS (CH * EPT)       // 20 events/thread capacity (1024*512*20=10.49M)
#define GWP (GW + 4)           // padded x-stride in p3 tile
#define CURSOR_BYTES 4096      // cursor[0..239] buckets, cursor[240] overflow
#define OF_RESERVE (512*1024)  // overflow list reserve at ws tail
#define MIN_CAPG 45056         // slots/bucket; exact counts mean 41.7K (+16s)
#define FXS 8192.0f            // fixed-point scale (2^13)

// Packed record: [q:16 | ylo:2 | pos:1 | xi:11], tn ~= q/65535, y = 3*g + ylo.

// ---------------- Phase 2: bucket events by y/3 (chunked two-pass) ----------
__global__ void p2_bucket(
        const float4* __restrict__ ev, int n,
        unsigned* __restrict__ cursor, unsigned* __restrict__ bucket,
        unsigned* __restrict__ oflist, int ofcap, int capg,
        const int* __restrict__ ct_p, const int* __restrict__ dt_p) {
    __shared__ unsigned hist[NGRP];
    __shared__ unsigned base[NGRP];

    const int chunk = (n + gridDim.x - 1) / gridDim.x;
    const int start = blockIdx.x * chunk;
    const int end   = min(n, start + chunk);
    const int tid   = (int)threadIdx.x;

    if (tid < NGRP) hist[tid] = 0u;
    __syncthreads();

    const int ct  = *ct_p;
    const int dti = *dt_p;
    const float bt  = (float)(ct - dti);
    const float dtf = (float)(dti + DT_OFFSET);

    for (int c = 0; c < CH; ++c) {
        // pass A: load + decode (registers), count via hist atomic (memoize j)
        unsigned wk[EPT];
        int      gj[EPT];   // (j << 8) | g, -1 = invalid
        #pragma unroll
        for (int k = 0; k < EPT; ++k) {
            int i = start + tid + (c * EPT + k) * TB2;
            gj[k] = -1;
            if (i < end) {
                float4 ee = ev[i];
                int yi  = (int)ee.z;
                int xi  = (int)ee.y;
                int pos = (ee.w > 0.0f) ? 1 : 0;
                int g   = yi / 3;
                int ylo = yi - 3 * g;
                float tn = (ee.x - bt) / dtf;          // in [0, 1)
                unsigned q = (unsigned)(tn * 65535.0f + 0.5f);
                if (q > 65535u) q = 65535u;
                wk[k] = (q << 14) | ((unsigned)ylo << 12)
                      | ((unsigned)pos << 11) | (unsigned)xi;
                unsigned j = atomicAdd(&hist[g], 1u);
                gj[k] = (int)((j << 8) | (unsigned)g);
            }
        }
        __syncthreads();

        // reserve EXACT runs (no padding, no zeroing); reset hist for next
        if (tid < NGRP) {
            unsigned cc = hist[tid];
            if (cc) base[tid] = atomicAdd(&cursor[tid], cc);
            hist[tid] = 0u;
        }
        __syncthreads();

        // pass B: pure store from registers
        #pragma unroll
        for (int k = 0; k < EPT; ++k) {
            if (gj[k] >= 0) {
                int      g = gj[k] & 255;
                unsigned j = (unsigned)gj[k] >> 8;
                unsigned slot = base[g] + j;
                if (slot < (unsigned)capg) {
                    bucket[(size_t)g * capg + slot] = wk[k];
                } else {
                    unsigned o = atomicAdd(&cursor[NGRP], 1u);
                    if (o < (unsigned)ofcap) {
                        oflist[2 * o]     = (unsigned)(3 * g + ((wk[k] >> 12) & 3u));
                        oflist[2 * o + 1] = wk[k];
                    }
                }
            }
        }
    }
}

// ---------------- Phase 3: two blocks per bucket (one per polarity) ---------
// Tile: per cell (ylo, x) 4 u32 words (bin-parity packed pairs).
// ONE ds_add_u32 per event.
__device__ __forceinline__ void p3_process(unsigned w, unsigned mypos,
                                           unsigned* tile) {
    if (w == 0u) return;                       // exact-zero event only
    if (((w >> 11) & 1u) != mypos) return;     // other polarity's block
    int   xi  = (int)(w & 0x7FFu);
    int   ylo = (int)((w >> 12) & 3u);
    float qf  = (float)(w >> 14);
    float tn  = qf * (1.0f / 65535.0f);
    float bf  = qf * (4.0f / 65535.0f);
    float back = floorf(bf);
    float fw   = bf - back;
    int   b    = (int)back;
    if (b > NUM_BINS - 2) b = NUM_BINS - 2;
    unsigned ql = (unsigned)((1.0f - fw) * tn * FXS + 0.5f);   // bin b
    unsigned qh = (unsigned)(fw * tn * FXS + 0.5f);            // bin b+1
    int   k   = ((b & 1) << 1) | (b >> 1);     // A0,A1,B0,B1 word select
    int   idx = (ylo * GWP + xi) * 4 + k;
    atomicAdd(&tile[idx], ql | (qh << 16));    // single ds_add_u32
}

__global__ __launch_bounds__(1024) void p3_accum(
        const unsigned* __restrict__ cursor, const unsigned* __restrict__ bucket,
        float* __restrict__ out, int capg) {
    __shared__ unsigned tile[3 * GWP * 4];     // 61,632 B (2 blocks/CU)
    const int      g     = blockIdx.x % NGRP;
    const unsigned mypos = (unsigned)(blockIdx.x / NGRP);

    for (int k = threadIdx.x; k < 3 * GWP * 4; k += blockDim.x)
        tile[k] = 0u;
    __syncthreads();

    unsigned cnt = cursor[g];
    if (cnt > (unsigned)capg) cnt = (unsigned)capg;   // rest went to overflow
    const unsigned* bk = bucket + (size_t)g * capg;
    const uint4* bk4 = (const uint4*)bk;
    unsigned n4 = cnt / 4;

    // batch 4 independent uint4 loads per outer iteration (MLP 4x):
    const uint4 z4 = make_uint4(0u, 0u, 0u, 0u);
    for (unsigned j0 = threadIdx.x; j0 < n4; j0 += 4u * 1024u) {
        unsigned j1 = j0 + 1024u, j2 = j0 + 2048u, j3 = j0 + 3072u;
        uint4 a = bk4[j0];
        uint4 b = (j1 < n4) ? bk4[j1] : z4;
        uint4 c = (j2 < n4) ? bk4[j2] : z4;
        uint4 d = (j3 < n4) ? bk4[j3] : z4;
        p3_process(a.x, mypos, tile); p3_process(a.y, mypos, tile);
        p3_process(a.z, mypos, tile); p3_process(a.w, mypos, tile);
        p3_process(b.x, mypos, tile); p3_process(b.y, mypos, tile);
        p3_process(b.z, mypos, tile); p3_process(b.w, mypos, tile);
        p3_process(c.x, mypos, tile); p3_process(c.y, mypos, tile);
        p3_process(c.z, mypos, tile); p3_process(c.w, mypos, tile);
        p3_process(d.x, mypos, tile); p3_process(d.y, mypos, tile);
        p3_process(d.z, mypos, tile); p3_process(d.w, mypos, tile);
    }
    // scalar tail: cnt is not a multiple of 16
    for (unsigned j = n4 * 4 + threadIdx.x; j < cnt; j += 1024)
        p3_process(bk[j], mypos, tile);
    __syncthreads();

    // writeout: per output float4, gather 4 cells, sum u16 halves, rescale
    for (int k = threadIdx.x; k < NUM_BINS * 3 * (GW / 4); k += blockDim.x) {
        int r   = k / (GW / 4);       // 0..14 = b*3 + ylo
        int x4  = k % (GW / 4);
        int b   = r / 3;
        int ylo = r - 3 * b;
        int y   = 3 * g + ylo;
        float4 o;
        float* po = (float*)&o;
        #pragma unroll
        for (int j = 0; j < 4; ++j) {
            int cidx = ylo * GWP + (x4 * 4 + j);
            uint4 wv = *(const uint4*)&tile[cidx * 4];
            unsigned v;
            if      (b == 0) v = (wv.x & 0xFFFFu);
            else if (b == 1) v = (wv.x >> 16) + (wv.z & 0xFFFFu);
            else if (b == 2) v = (wv.y & 0xFFFFu) + (wv.z >> 16);
            else if (b == 3) v = (wv.y >> 16) + (wv.w & 0xFFFFu);
            else             v = (wv.w >> 16);
            po[j] = (float)v * (1.0f / FXS);
        }
        ((float4*)(out + ((size_t)(b * 2 + (int)mypos) * GH + y) * GW))[x4] = o;
    }
}

// ---------------- Phase 4: drain overflow list (usually empty) --------------
__global__ void p4_overflow(const unsigned* __restrict__ cursor,
                            const unsigned* __restrict__ oflist, int ofcap,
                            float* __restrict__ out) {
    unsigned nof = cursor[NGRP];
    if (nof > (unsigned)ofcap) nof = (unsigned)ofcap;
    for (unsigned k = blockIdx.x * blockDim.x + threadIdx.x; k < nof;
         k += gridDim.x * blockDim.x) {
        unsigned yi = oflist[2 * k];
        unsigned w  = oflist[2 * k + 1];
        int   xi  = (int)(w & 0x7FFu);
        int   pos = (int)((w >> 11) & 1u);
        float tn  = (float)(w >> 14) * (1.0f / 65535.0f);
        float bf  = (NUM_BINS - 1.0f) * tn;
        float back = floorf(bf);
        float fw   = bf - back;
        int   b    = (int)back;
        if (b > NUM_BINS - 2) b = NUM_BINS - 2;
        atomicAdd(&out[((size_t)(b * 2 + pos) * GH + yi) * GW + xi],
                  (1.0f - fw) * tn);
        atomicAdd(&out[((size_t)((b + 1) * 2 + pos) * GH + yi) * GW + xi],
                  fw * tn);
    }
}

// ---------------- Fallback: R1 naive atomic kernel (if ws too small) --------
__global__ void voxel_scatter_kernel(const float4* __restrict__ events,
                                     float* __restrict__ out, int n,
                                     const int* __restrict__ ct_p,
                                     const int* __restrict__ dt_p,
                                     const int* __restrict__ w_p,
                                     const int* __restrict__ h_p) {
    int i = blockIdx.x * blockDim.x + threadIdx.x;
    if (i >= n) return;
    const int ct = *ct_p, dti = *dt_p, W = *w_p, H = *h_p;
    const float bt  = (float)(ct - dti);
    const float dtf = (float)(dti + DT_OFFSET);
    float4 e = events[i];
    const float tn    = (e.x - bt) / dtf;
    const float bin_f = (NUM_BINS - 1.0f) * tn;
    const float back  = floorf(bin_f);
    const float fwd_w = bin_f - back;
    const int back_i = (int)back;
    const int pos    = (e.w > 0.0f) ? 1 : 0;
    const int xi = (int)e.y, yi = (int)e.z;
    const int plane = H * W, slab = 2 * plane;
    const int base = (back_i * 2 + pos) * plane + yi * W + xi;
    atomicAdd(&out[base],        (1.0f - fwd_w) * tn);
    atomicAdd(&out[base + slab], fwd_w * tn);
}

extern "C" void kernel_launch(void* const* d_in, const int* in_sizes, int n_in,
                              void* d_out, int out_size, void* d_ws, size_t ws_size,
                              hipStream_t stream) {
    const float4* events = (const float4*)d_in[0];
    const int* curr_time = (const int*)d_in[1];
    const int* delta_t   = (const int*)d_in[2];
    const int* width     = (const int*)d_in[3];
    const int* height    = (const int*)d_in[4];
    float* out = (float*)d_out;
    const int n = in_sizes[0] / 4;

    // ws layout: [cursor 4KB][bucket NGRP*capg*4B][overflow list (rest)]
    int capg = 0;
    if (ws_size > CURSOR_BYTES + OF_RESERVE)
        capg = (int)(((ws_size - CURSOR_BYTES - OF_RESERVE)
                      / (NGRP * sizeof(unsigned))) & ~(size_t)15);

    if (capg >= MIN_CAPG && n <= NB2 * TB2 * ITERS) {
        unsigned* cursor = (unsigned*)d_ws;
        unsigned* bucket = (unsigned*)((char*)d_ws + CURSOR_BYTES);
        unsigned* oflist = bucket + (size_t)NGRP * capg;
        int ofcap = (int)((ws_size - CURSOR_BYTES
                           - (size_t)NGRP * capg * sizeof(unsigned))
                          / (2 * sizeof(unsigned)));
        hipMemsetAsync(cursor, 0, CURSOR_BYTES, stream);
        p2_bucket<<<NB2, TB2, 0, stream>>>(events, n, cursor, bucket,
                                           oflist, ofcap, capg,
                                           curr_time, delta_t);
        p3_accum<<<2 * NGRP, 1024, 0, stream>>>(cursor, bucket, out, capg);
        p4_overflow<<<64, 256, 0, stream>>>(cursor, oflist, ofcap, out);
    } else {
        hipMemsetAsync(out, 0, (size_t)out_size * sizeof(float), stream);
        const int block = 256;
        const int grid  = (n + block - 1) / block;
        voxel_scatter_kernel<<<grid, block, 0, stream>>>(events, out, n,
                                                         curr_time, delta_t,
                                                         width, height);
    }
}

// Round 8
// 315.379 us; speedup vs baseline: 1.0172x; 1.0172x over previous
//
#include <hip/hip_runtime.h>
#include <hip/hip_bf16.h>

// VoxelGrid: 10M events -> (10, 720, 1280) fp32 grid, bilinear splat in time.
// R1: naive 20M device atomics -> 958 us. R2-R5: bucket sort evolution -> 415.
// R10: polarity split: p3 is LDS-atomic-MESSAGE throughput bound
//   (~3.3 cyc/msg/CU), not latency.
// R11: ONE packed ds_add_u32 per event (16b fixed point, bin-parity words)
//   -> p3 ~116 -> ~40 us. Model CONFIRMED. Total 395 -> 310.
// R12: memoized hist-return j (20M->10M LDS msgs): p2 UNCHANGED; wk/gj in
//   scratch (WRITE 150MB). p2 NOT atomic-count-bound.
// R13: chunked staging (5x8/thr, 1024 thr, launch_bounds(1024)) -> clean
//   VGPR 36, WRITE 52MB, p2 108. Occupancy 41% was GRID-limited (NB2=256
//   = exactly 1 block/CU; VGPR 36 admits 2).
// R14: launch_bounds(1024,8) -> allocator spilled staging (VGPR 20) -> 122.
// R15: 512thr/EPT=10/no-bounds -> default 64-VGPR budget spilled again
//   (VGPR 20, WRITE 82MB) -> 127. EPT=8@1024thr+bounds(1024) is the one
//   proven no-spill shape.
// R16: NB2=512 clean-TLP test crashed in pytest (core dump, no counters).
//   Audit found no OOB/race; diff from proven R13 codegen = dropped
//   launch_bounds(1024). R17 = R16 rerun with the attribute pinned.

#define NUM_BINS 5
#define DT_OFFSET 1
#define GW 1280
#define GH 720
#define NSLAB (NUM_BINS * 2)   // 10 (bin, polarity) slabs in the OUTPUT
#define NGRP 240               // coarse buckets (y/3)
#define NB2 512                // phase-2 blocks (2 per CU by grid)
#define CH 3                   // chunks per block
#define EPT 8                  // events per thread per chunk (proven no-spill)
#define ITERS (CH * EPT)       // 24 events/thread capacity (512*1024*24=12.6M)
#define GWP (GW + 4)           // padded x-stride in p3 tile
#define CURSOR_BYTES 4096      // cursor[0..239] buckets, cursor[240] overflow
#define OF_RESERVE (512*1024)  // overflow list reserve at ws tail
#define MIN_CAPG 45056         // slots/bucket; exact counts mean 41.7K (+16s)
#define FXS 8192.0f            // fixed-point scale (2^13)

// Packed record: [q:16 | ylo:2 | pos:1 | xi:11], tn ~= q/65535, y = 3*g + ylo.

// ---------------- Phase 2: bucket events by y/3 (chunked two-pass) ----------
__global__ __launch_bounds__(1024) void p2_bucket(
        const float4* __restrict__ ev, int n,
        unsigned* __restrict__ cursor, unsigned* __restrict__ bucket,
        unsigned* __restrict__ oflist, int ofcap, int capg,
        const int* __restrict__ ct_p, const int* __restrict__ dt_p) {
    __shared__ unsigned hist[NGRP];
    __shared__ unsigned base[NGRP];

    const int chunk = (n + gridDim.x - 1) / gridDim.x;
    const int start = blockIdx.x * chunk;
    const int end   = min(n, start + chunk);
    const int tid   = (int)threadIdx.x;

    if (tid < NGRP) hist[tid] = 0u;
    __syncthreads();

    const int ct  = *ct_p;
    const int dti = *dt_p;
    const float bt  = (float)(ct - dti);
    const float dtf = (float)(dti + DT_OFFSET);

    // prologue: load chunk 0's events (R13 structure)
    float4 e[EPT];
    #pragma unroll
    for (int k = 0; k < EPT; ++k) {
        int i = start + tid + k * 1024;
        if (i < end) e[k] = ev[i];
    }

    for (int c = 0; c < CH; ++c) {
        // pass A: decode (registers only), count via hist atomic (memoize j)
        unsigned wk[EPT];
        int      gj[EPT];   // (j << 8) | g, -1 = invalid
        #pragma unroll
        for (int k = 0; k < EPT; ++k) {
            int i = start + tid + (c * EPT + k) * 1024;
            gj[k] = -1;
            if (i < end) {
                float4 ee = e[k];
                int yi  = (int)ee.z;
                int xi  = (int)ee.y;
                int pos = (ee.w > 0.0f) ? 1 : 0;
                int g   = yi / 3;
                int ylo = yi - 3 * g;
                float tn = (ee.x - bt) / dtf;          // in [0, 1)
                unsigned q = (unsigned)(tn * 65535.0f + 0.5f);
                if (q > 65535u) q = 65535u;
                wk[k] = (q << 14) | ((unsigned)ylo << 12)
                      | ((unsigned)pos << 11) | (unsigned)xi;
                unsigned j = atomicAdd(&hist[g], 1u);
                gj[k] = (int)((j << 8) | (unsigned)g);
            }
        }
        __syncthreads();

        // reserve EXACT runs (no padding, no zeroing); reset hist for next
        if (tid < NGRP) {
            unsigned cc = hist[tid];
            if (cc) base[tid] = atomicAdd(&cursor[tid], cc);
            hist[tid] = 0u;
        }
        __syncthreads();

        // prefetch next chunk's events (latency hides under the stores)
        if (c + 1 < CH) {
            #pragma unroll
            for (int k = 0; k < EPT; ++k) {
                int i = start + tid + ((c + 1) * EPT + k) * 1024;
                if (i < end) e[k] = ev[i];
            }
        }

        // pass B: pure store from registers
        #pragma unroll
        for (int k = 0; k < EPT; ++k) {
            if (gj[k] >= 0) {
                int      g = gj[k] & 255;
                unsigned j = (unsigned)gj[k] >> 8;
                unsigned slot = base[g] + j;
                if (slot < (unsigned)capg) {
                    bucket[(size_t)g * capg + slot] = wk[k];
                } else {
                    unsigned o = atomicAdd(&cursor[NGRP], 1u);
                    if (o < (unsigned)ofcap) {
                        oflist[2 * o]     = (unsigned)(3 * g + ((wk[k] >> 12) & 3u));
                        oflist[2 * o + 1] = wk[k];
                    }
                }
            }
        }
    }
}

// ---------------- Phase 3: two blocks per bucket (one per polarity) ---------
// Tile: per cell (ylo, x) 4 u32 words (bin-parity packed pairs).
// ONE ds_add_u32 per event.
__device__ __forceinline__ void p3_process(unsigned w, unsigned mypos,
                                           unsigned* tile) {
    if (w == 0u) return;                       // exact-zero event only
    if (((w >> 11) & 1u) != mypos) return;     // other polarity's block
    int   xi  = (int)(w & 0x7FFu);
    int   ylo = (int)((w >> 12) & 3u);
    float qf  = (float)(w >> 14);
    float tn  = qf * (1.0f / 65535.0f);
    float bf  = qf * (4.0f / 65535.0f);
    float back = floorf(bf);
    float fw   = bf - back;
    int   b    = (int)back;
    if (b > NUM_BINS - 2) b = NUM_BINS - 2;
    unsigned ql = (unsigned)((1.0f - fw) * tn * FXS + 0.5f);   // bin b
    unsigned qh = (unsigned)(fw * tn * FXS + 0.5f);            // bin b+1
    int   k   = ((b & 1) << 1) | (b >> 1);     // A0,A1,B0,B1 word select
    int   idx = (ylo * GWP + xi) * 4 + k;
    atomicAdd(&tile[idx], ql | (qh << 16));    // single ds_add_u32
}

__global__ __launch_bounds__(1024) void p3_accum(
        const unsigned* __restrict__ cursor, const unsigned* __restrict__ bucket,
        float* __restrict__ out, int capg) {
    __shared__ unsigned tile[3 * GWP * 4];     // 61,632 B (2 blocks/CU)
    const int      g     = blockIdx.x % NGRP;
    const unsigned mypos = (unsigned)(blockIdx.x / NGRP);

    for (int k = threadIdx.x; k < 3 * GWP * 4; k += blockDim.x)
        tile[k] = 0u;
    __syncthreads();

    unsigned cnt = cursor[g];
    if (cnt > (unsigned)capg) cnt = (unsigned)capg;   // rest went to overflow
    const unsigned* bk = bucket + (size_t)g * capg;
    const uint4* bk4 = (const uint4*)bk;
    unsigned n4 = cnt / 4;

    // batch 4 independent uint4 loads per outer iteration (MLP 4x):
    const uint4 z4 = make_uint4(0u, 0u, 0u, 0u);
    for (unsigned j0 = threadIdx.x; j0 < n4; j0 += 4u * 1024u) {
        unsigned j1 = j0 + 1024u, j2 = j0 + 2048u, j3 = j0 + 3072u;
        uint4 a = bk4[j0];
        uint4 b = (j1 < n4) ? bk4[j1] : z4;
        uint4 c = (j2 < n4) ? bk4[j2] : z4;
        uint4 d = (j3 < n4) ? bk4[j3] : z4;
        p3_process(a.x, mypos, tile); p3_process(a.y, mypos, tile);
        p3_process(a.z, mypos, tile); p3_process(a.w, mypos, tile);
        p3_process(b.x, mypos, tile); p3_process(b.y, mypos, tile);
        p3_process(b.z, mypos, tile); p3_process(b.w, mypos, tile);
        p3_process(c.x, mypos, tile); p3_process(c.y, mypos, tile);
        p3_process(c.z, mypos, tile); p3_process(c.w, mypos, tile);
        p3_process(d.x, mypos, tile); p3_process(d.y, mypos, tile);
        p3_process(d.z, mypos, tile); p3_process(d.w, mypos, tile);
    }
    // scalar tail: cnt is not a multiple of 16
    for (unsigned j = n4 * 4 + threadIdx.x; j < cnt; j += 1024)
        p3_process(bk[j], mypos, tile);
    __syncthreads();

    // writeout: per output float4, gather 4 cells, sum u16 halves, rescale
    for (int k = threadIdx.x; k < NUM_BINS * 3 * (GW / 4); k += blockDim.x) {
        int r   = k / (GW / 4);       // 0..14 = b*3 + ylo
        int x4  = k % (GW / 4);
        int b   = r / 3;
        int ylo = r - 3 * b;
        int y   = 3 * g + ylo;
        float4 o;
        float* po = (float*)&o;
        #pragma unroll
        for (int j = 0; j < 4; ++j) {
            int cidx = ylo * GWP + (x4 * 4 + j);
            uint4 wv = *(const uint4*)&tile[cidx * 4];
            unsigned v;
            if      (b == 0) v = (wv.x & 0xFFFFu);
            else if (b == 1) v = (wv.x >> 16) + (wv.z & 0xFFFFu);
            else if (b == 2) v = (wv.y & 0xFFFFu) + (wv.z >> 16);
            else if (b == 3) v = (wv.y >> 16) + (wv.w & 0xFFFFu);
            else             v = (wv.w >> 16);
            po[j] = (float)v * (1.0f / FXS);
        }
        ((float4*)(out + ((size_t)(b * 2 + (int)mypos) * GH + y) * GW))[x4] = o;
    }
}

// ---------------- Phase 4: drain overflow list (usually empty) --------------
__global__ void p4_overflow(const unsigned* __restrict__ cursor,
                            const unsigned* __restrict__ oflist, int ofcap,
                            float* __restrict__ out) {
    unsigned nof = cursor[NGRP];
    if (nof > (unsigned)ofcap) nof = (unsigned)ofcap;
    for (unsigned k = blockIdx.x * blockDim.x + threadIdx.x; k < nof;
         k += gridDim.x * blockDim.x) {
        unsigned yi = oflist[2 * k];
        unsigned w  = oflist[2 * k + 1];
        int   xi  = (int)(w & 0x7FFu);
        int   pos = (int)((w >> 11) & 1u);
        float tn  = (float)(w >> 14) * (1.0f / 65535.0f);
        float bf  = (NUM_BINS - 1.0f) * tn;
        float back = floorf(bf);
        float fw   = bf - back;
        int   b    = (int)back;
        if (b > NUM_BINS - 2) b = NUM_BINS - 2;
        atomicAdd(&out[((size_t)(b * 2 + pos) * GH + yi) * GW + xi],
                  (1.0f - fw) * tn);
        atomicAdd(&out[((size_t)((b + 1) * 2 + pos) * GH + yi) * GW + xi],
                  fw * tn);
    }
}

// ---------------- Fallback: R1 naive atomic kernel (if ws too small) --------
__global__ void voxel_scatter_kernel(const float4* __restrict__ events,
                                     float* __restrict__ out, int n,
                                     const int* __restrict__ ct_p,
                                     const int* __restrict__ dt_p,
                                     const int* __restrict__ w_p,
                                     const int* __restrict__ h_p) {
    int i = blockIdx.x * blockDim.x + threadIdx.x;
    if (i >= n) return;
    const int ct = *ct_p, dti = *dt_p, W = *w_p, H = *h_p;
    const float bt  = (float)(ct - dti);
    const float dtf = (float)(dti + DT_OFFSET);
    float4 e = events[i];
    const float tn    = (e.x - bt) / dtf;
    const float bin_f = (NUM_BINS - 1.0f) * tn;
    const float back  = floorf(bin_f);
    const float fwd_w = bin_f - back;
    const int back_i = (int)back;
    const int pos    = (e.w > 0.0f) ? 1 : 0;
    const int xi = (int)e.y, yi = (int)e.z;
    const int plane = H * W, slab = 2 * plane;
    const int base = (back_i * 2 + pos) * plane + yi * W + xi;
    atomicAdd(&out[base],        (1.0f - fwd_w) * tn);
    atomicAdd(&out[base + slab], fwd_w * tn);
}

extern "C" void kernel_launch(void* const* d_in, const int* in_sizes, int n_in,
                              void* d_out, int out_size, void* d_ws, size_t ws_size,
                              hipStream_t stream) {
    const float4* events = (const float4*)d_in[0];
    const int* curr_time = (const int*)d_in[1];
    const int* delta_t   = (const int*)d_in[2];
    const int* width     = (const int*)d_in[3];
    const int* height    = (const int*)d_in[4];
    float* out = (float*)d_out;
    const int n = in_sizes[0] / 4;

    // ws layout: [cursor 4KB][bucket NGRP*capg*4B][overflow list (rest)]
    int capg = 0;
    if (ws_size > CURSOR_BYTES + OF_RESERVE)
        capg = (int)(((ws_size - CURSOR_BYTES - OF_RESERVE)
                      / (NGRP * sizeof(unsigned))) & ~(size_t)15);

    if (capg >= MIN_CAPG && n <= NB2 * 1024 * ITERS) {
        unsigned* cursor = (unsigned*)d_ws;
        unsigned* bucket = (unsigned*)((char*)d_ws + CURSOR_BYTES);
        unsigned* oflist = bucket + (size_t)NGRP * capg;
        int ofcap = (int)((ws_size - CURSOR_BYTES
                           - (size_t)NGRP * capg * sizeof(unsigned))
                          / (2 * sizeof(unsigned)));
        hipMemsetAsync(cursor, 0, CURSOR_BYTES, stream);
        p2_bucket<<<NB2, 1024, 0, stream>>>(events, n, cursor, bucket,
                                            oflist, ofcap, capg,
                                            curr_time, delta_t);
        p3_accum<<<2 * NGRP, 1024, 0, stream>>>(cursor, bucket, out, capg);
        p4_overflow<<<64, 256, 0, stream>>>(cursor, oflist, ofcap, out);
    } else {
        hipMemsetAsync(out, 0, (size_t)out_size * sizeof(float), stream);
        const int block = 256;
        const int grid  = (n + block - 1) / block;
        voxel_scatter_kernel<<<grid, block, 0, stream>>>(events, out, n,
                                                         curr_time, delta_t,
                                                         width, height);
    }
}

// Round 9
// 308.594 us; speedup vs baseline: 1.0396x; 1.0220x over previous
//
#include <hip/hip_runtime.h>
#include <hip/hip_bf16.h>

// VoxelGrid: 10M events -> (10, 720, 1280) fp32 grid, bilinear splat in time.
// R1: naive 20M device atomics -> 958 us. R2-R5: bucket sort evolution -> 415.
// R10: polarity split: p3 LDS-atomic-MESSAGE bound, not latency.
// R11: ONE packed ds_add_u32 per event -> p3 ~116 -> ~40. Total 395 -> 310.
//   (Halving msgs gave 2.9x, not 2x -> waits mattered, not just msg rate.)
// R12: memoized hist-return j: p2 unchanged; staging spilled (WRITE 150MB).
// R13: chunked staging (5x8/thr, 1024thr, bounds(1024)): VGPR 36, WRITE
//   52MB, p2 108. BEST p2 geometry.
// R14/R15: launch_bounds(1024,8) / 512thr+EPT10 -> allocator spill (VGPR
//   20) -> 122/127. EPT=8@1024thr+bounds(1024) is the no-spill shape.
// R16: crash (no counters). R17 = R16 + pinned bounds: CLEAN (VGPR 32,
//   occ 70%, 2 blk/CU) but p2 113 -> TLP phase overlap DOESN'T pay:
//   homogeneous blocks run phases in LOCKSTEP (both hammer LDS in pass A
//   together, then both store). Budget: ~50us atomic-busy + ~55us mem/VALU
//   on OTHER pipes, measured 108-113 -> phases run ~serially INSIDE the
//   wave: guarded per-event {load->decode->rtn-atomic->use} chains eat
//   LDS round-trip latency per event.
// R18: pipeline the rtn-atomics. R13 geometry (NB2=256, CH=5, EPT=8,
//   bounds(1024)). For full chunks (255/256 blocks): branch-free 3-loop
//   pass A: [8x load+decode] [8x atomicAdd back-to-back] [8x pack] ->
//   8 ds_add_rtn in flight, one drain. Unguarded pass-B fast path.
//   B(c) and A(c+1) share a barrier-free region (loop-back) for
//   cross-stream overlap.

#define NUM_BINS 5
#define DT_OFFSET 1
#define GW 1280
#define GH 720
#define NSLAB (NUM_BINS * 2)   // 10 (bin, polarity) slabs in the OUTPUT
#define NGRP 240               // coarse buckets (y/3)
#define NB2 256                // phase-2 blocks (R13 geometry)
#define CH 5                   // chunks per block
#define EPT 8                  // events per thread per chunk (no-spill shape)
#define ITERS (CH * EPT)       // 40 events/thread capacity
#define GWP (GW + 4)           // padded x-stride in p3 tile
#define CURSOR_BYTES 4096      // cursor[0..239] buckets, cursor[240] overflow
#define OF_RESERVE (512*1024)  // overflow list reserve at ws tail
#define MIN_CAPG 45056         // slots/bucket; exact counts mean 41.7K
#define FXS 8192.0f            // fixed-point scale (2^13)

// Packed record: [q:16 | ylo:2 | pos:1 | xi:11], tn ~= q/65535, y = 3*g + ylo.

__device__ __forceinline__ void p2_decode(float4 ee, float bt, float dtf,
                                          unsigned* w, unsigned* g) {
    int yi  = (int)ee.z;
    int xi  = (int)ee.y;
    int pos = (ee.w > 0.0f) ? 1 : 0;
    int gg  = yi / 3;
    int ylo = yi - 3 * gg;
    float tn = (ee.x - bt) / dtf;              // in [0, 1)
    unsigned q = (unsigned)(tn * 65535.0f + 0.5f);
    if (q > 65535u) q = 65535u;
    *w = (q << 14) | ((unsigned)ylo << 12) | ((unsigned)pos << 11)
       | (unsigned)xi;
    *g = (unsigned)gg;
}

// ---------------- Phase 2: bucket events by y/3 (chunked two-pass) ----------
__global__ __launch_bounds__(1024) void p2_bucket(
        const float4* __restrict__ ev, int n,
        unsigned* __restrict__ cursor, unsigned* __restrict__ bucket,
        unsigned* __restrict__ oflist, int ofcap, int capg,
        const int* __restrict__ ct_p, const int* __restrict__ dt_p) {
    __shared__ unsigned hist[NGRP];
    __shared__ unsigned base[NGRP];

    const int chunk = (n + gridDim.x - 1) / gridDim.x;
    const int start = blockIdx.x * chunk;
    const int end   = min(n, start + chunk);
    const int tid   = (int)threadIdx.x;

    if (tid < NGRP) hist[tid] = 0u;
    __syncthreads();

    const int ct  = *ct_p;
    const int dti = *dt_p;
    const float bt  = (float)(ct - dti);
    const float dtf = (float)(dti + DT_OFFSET);

    for (int c = 0; c < CH; ++c) {
        unsigned wk[EPT];
        int      gj[EPT];   // (j << 8) | g, -1 = invalid
        const int ibase = start + tid + (c * EPT) * 1024;
        // block-uniform: is every lane's k-th index in range for all k?
        const bool full = (start + (c * EPT + EPT) * 1024) <= end;

        if (full) {
            // ---- pass A fast path: 3 split loops, branch-free ----
            unsigned gg[EPT];
            unsigned jr[EPT];
            #pragma unroll
            for (int k = 0; k < EPT; ++k) {
                float4 ee = ev[ibase + k * 1024];
                p2_decode(ee, bt, dtf, &wk[k], &gg[k]);
            }
            #pragma unroll
            for (int k = 0; k < EPT; ++k)
                jr[k] = atomicAdd(&hist[gg[k]], 1u);   // 8 rtn-atomics in flight
            #pragma unroll
            for (int k = 0; k < EPT; ++k)
                gj[k] = (int)((jr[k] << 8) | gg[k]);
        } else {
            // ---- guarded path (last partial chunk of last block) ----
            #pragma unroll
            for (int k = 0; k < EPT; ++k) {
                int i = ibase + k * 1024;
                gj[k] = -1;
                if (i < end) {
                    unsigned w, g;
                    p2_decode(ev[i], bt, dtf, &w, &g);
                    wk[k] = w;
                    unsigned j = atomicAdd(&hist[g], 1u);
                    gj[k] = (int)((j << 8) | g);
                }
            }
        }
        __syncthreads();

        // reserve EXACT runs; reset hist for next chunk
        if (tid < NGRP) {
            unsigned cc = hist[tid];
            if (cc) base[tid] = atomicAdd(&cursor[tid], cc);
            hist[tid] = 0u;
        }
        __syncthreads();

        // ---- pass B: pure stores; shares region with next chunk's pass A ----
        if (full) {
            #pragma unroll
            for (int k = 0; k < EPT; ++k) {
                int      g = gj[k] & 255;
                unsigned j = (unsigned)gj[k] >> 8;
                unsigned slot = base[g] + j;
                if (slot < (unsigned)capg) {
                    bucket[(size_t)g * capg + slot] = wk[k];
                } else {
                    unsigned o = atomicAdd(&cursor[NGRP], 1u);
                    if (o < (unsigned)ofcap) {
                        oflist[2 * o]     = (unsigned)(3 * g + ((wk[k] >> 12) & 3u));
                        oflist[2 * o + 1] = wk[k];
                    }
                }
            }
        } else {
            #pragma unroll
            for (int k = 0; k < EPT; ++k) {
                if (gj[k] >= 0) {
                    int      g = gj[k] & 255;
                    unsigned j = (unsigned)gj[k] >> 8;
                    unsigned slot = base[g] + j;
                    if (slot < (unsigned)capg) {
                        bucket[(size_t)g * capg + slot] = wk[k];
                    } else {
                        unsigned o = atomicAdd(&cursor[NGRP], 1u);
                        if (o < (unsigned)ofcap) {
                            oflist[2 * o]     = (unsigned)(3 * g + ((wk[k] >> 12) & 3u));
                            oflist[2 * o + 1] = wk[k];
                        }
                    }
                }
            }
        }
    }
}

// ---------------- Phase 3: two blocks per bucket (one per polarity) ---------
// Tile: per cell (ylo, x) 4 u32 words (bin-parity packed pairs).
// ONE ds_add_u32 per event.
__device__ __forceinline__ void p3_process(unsigned w, unsigned mypos,
                                           unsigned* tile) {
    if (w == 0u) return;                       // exact-zero event only
    if (((w >> 11) & 1u) != mypos) return;     // other polarity's block
    int   xi  = (int)(w & 0x7FFu);
    int   ylo = (int)((w >> 12) & 3u);
    float qf  = (float)(w >> 14);
    float tn  = qf * (1.0f / 65535.0f);
    float bf  = qf * (4.0f / 65535.0f);
    float back = floorf(bf);
    float fw   = bf - back;
    int   b    = (int)back;
    if (b > NUM_BINS - 2) b = NUM_BINS - 2;
    unsigned ql = (unsigned)((1.0f - fw) * tn * FXS + 0.5f);   // bin b
    unsigned qh = (unsigned)(fw * tn * FXS + 0.5f);            // bin b+1
    int   k   = ((b & 1) << 1) | (b >> 1);     // A0,A1,B0,B1 word select
    int   idx = (ylo * GWP + xi) * 4 + k;
    atomicAdd(&tile[idx], ql | (qh << 16));    // single ds_add_u32
}

__global__ __launch_bounds__(1024) void p3_accum(
        const unsigned* __restrict__ cursor, const unsigned* __restrict__ bucket,
        float* __restrict__ out, int capg) {
    __shared__ unsigned tile[3 * GWP * 4];     // 61,632 B (2 blocks/CU)
    const int      g     = blockIdx.x % NGRP;
    const unsigned mypos = (unsigned)(blockIdx.x / NGRP);

    for (int k = threadIdx.x; k < 3 * GWP * 4; k += blockDim.x)
        tile[k] = 0u;
    __syncthreads();

    unsigned cnt = cursor[g];
    if (cnt > (unsigned)capg) cnt = (unsigned)capg;   // rest went to overflow
    const unsigned* bk = bucket + (size_t)g * capg;
    const uint4* bk4 = (const uint4*)bk;
    unsigned n4 = cnt / 4;

    // batch 4 independent uint4 loads per outer iteration (MLP 4x):
    const uint4 z4 = make_uint4(0u, 0u, 0u, 0u);
    for (unsigned j0 = threadIdx.x; j0 < n4; j0 += 4u * 1024u) {
        unsigned j1 = j0 + 1024u, j2 = j0 + 2048u, j3 = j0 + 3072u;
        uint4 a = bk4[j0];
        uint4 b = (j1 < n4) ? bk4[j1] : z4;
        uint4 c = (j2 < n4) ? bk4[j2] : z4;
        uint4 d = (j3 < n4) ? bk4[j3] : z4;
        p3_process(a.x, mypos, tile); p3_process(a.y, mypos, tile);
        p3_process(a.z, mypos, tile); p3_process(a.w, mypos, tile);
        p3_process(b.x, mypos, tile); p3_process(b.y, mypos, tile);
        p3_process(b.z, mypos, tile); p3_process(b.w, mypos, tile);
        p3_process(c.x, mypos, tile); p3_process(c.y, mypos, tile);
        p3_process(c.z, mypos, tile); p3_process(c.w, mypos, tile);
        p3_process(d.x, mypos, tile); p3_process(d.y, mypos, tile);
        p3_process(d.z, mypos, tile); p3_process(d.w, mypos, tile);
    }
    // scalar tail: cnt is not a multiple of 16
    for (unsigned j = n4 * 4 + threadIdx.x; j < cnt; j += 1024)
        p3_process(bk[j], mypos, tile);
    __syncthreads();

    // writeout: per output float4, gather 4 cells, sum u16 halves, rescale
    for (int k = threadIdx.x; k < NUM_BINS * 3 * (GW / 4); k += blockDim.x) {
        int r   = k / (GW / 4);       // 0..14 = b*3 + ylo
        int x4  = k % (GW / 4);
        int b   = r / 3;
        int ylo = r - 3 * b;
        int y   = 3 * g + ylo;
        float4 o;
        float* po = (float*)&o;
        #pragma unroll
        for (int j = 0; j < 4; ++j) {
            int cidx = ylo * GWP + (x4 * 4 + j);
            uint4 wv = *(const uint4*)&tile[cidx * 4];
            unsigned v;
            if      (b == 0) v = (wv.x & 0xFFFFu);
            else if (b == 1) v = (wv.x >> 16) + (wv.z & 0xFFFFu);
            else if (b == 2) v = (wv.y & 0xFFFFu) + (wv.z >> 16);
            else if (b == 3) v = (wv.y >> 16) + (wv.w & 0xFFFFu);
            else             v = (wv.w >> 16);
            po[j] = (float)v * (1.0f / FXS);
        }
        ((float4*)(out + ((size_t)(b * 2 + (int)mypos) * GH + y) * GW))[x4] = o;
    }
}

// ---------------- Phase 4: drain overflow list (usually empty) --------------
__global__ void p4_overflow(const unsigned* __restrict__ cursor,
                            const unsigned* __restrict__ oflist, int ofcap,
                            float* __restrict__ out) {
    unsigned nof = cursor[NGRP];
    if (nof > (unsigned)ofcap) nof = (unsigned)ofcap;
    for (unsigned k = blockIdx.x * blockDim.x + threadIdx.x; k < nof;
         k += gridDim.x * blockDim.x) {
        unsigned yi = oflist[2 * k];
        unsigned w  = oflist[2 * k + 1];
        int   xi  = (int)(w & 0x7FFu);
        int   pos = (int)((w >> 11) & 1u);
        float tn  = (float)(w >> 14) * (1.0f / 65535.0f);
        float bf  = (NUM_BINS - 1.0f) * tn;
        float back = floorf(bf);
        float fw   = bf - back;
        int   b    = (int)back;
        if (b > NUM_BINS - 2) b = NUM_BINS - 2;
        atomicAdd(&out[((size_t)(b * 2 + pos) * GH + yi) * GW + xi],
                  (1.0f - fw) * tn);
        atomicAdd(&out[((size_t)((b + 1) * 2 + pos) * GH + yi) * GW + xi],
                  fw * tn);
    }
}

// ---------------- Fallback: R1 naive atomic kernel (if ws too small) --------
__global__ void voxel_scatter_kernel(const float4* __restrict__ events,
                                     float* __restrict__ out, int n,
                                     const int* __restrict__ ct_p,
                                     const int* __restrict__ dt_p,
                                     const int* __restrict__ w_p,
                                     const int* __restrict__ h_p) {
    int i = blockIdx.x * blockDim.x + threadIdx.x;
    if (i >= n) return;
    const int ct = *ct_p, dti = *dt_p, W = *w_p, H = *h_p;
    const float bt  = (float)(ct - dti);
    const float dtf = (float)(dti + DT_OFFSET);
    float4 e = events[i];
    const float tn    = (e.x - bt) / dtf;
    const float bin_f = (NUM_BINS - 1.0f) * tn;
    const float back  = floorf(bin_f);
    const float fwd_w = bin_f - back;
    const int back_i = (int)back;
    const int pos    = (e.w > 0.0f) ? 1 : 0;
    const int xi = (int)e.y, yi = (int)e.z;
    const int plane = H * W, slab = 2 * plane;
    const int base = (back_i * 2 + pos) * plane + yi * W + xi;
    atomicAdd(&out[base],        (1.0f - fwd_w) * tn);
    atomicAdd(&out[base + slab], fwd_w * tn);
}

extern "C" void kernel_launch(void* const* d_in, const int* in_sizes, int n_in,
                              void* d_out, int out_size, void* d_ws, size_t ws_size,
                              hipStream_t stream) {
    const float4* events = (const float4*)d_in[0];
    const int* curr_time = (const int*)d_in[1];
    const int* delta_t   = (const int*)d_in[2];
    const int* width     = (const int*)d_in[3];
    const int* height    = (const int*)d_in[4];
    float* out = (float*)d_out;
    const int n = in_sizes[0] / 4;

    // ws layout: [cursor 4KB][bucket NGRP*capg*4B][overflow list (rest)]
    int capg = 0;
    if (ws_size > CURSOR_BYTES + OF_RESERVE)
        capg = (int)(((ws_size - CURSOR_BYTES - OF_RESERVE)
                      / (NGRP * sizeof(unsigned))) & ~(size_t)15);

    if (capg >= MIN_CAPG && n <= NB2 * 1024 * ITERS) {
        unsigned* cursor = (unsigned*)d_ws;
        unsigned* bucket = (unsigned*)((char*)d_ws + CURSOR_BYTES);
        unsigned* oflist = bucket + (size_t)NGRP * capg;
        int ofcap = (int)((ws_size - CURSOR_BYTES
                           - (size_t)NGRP * capg * sizeof(unsigned))
                          / (2 * sizeof(unsigned)));
        hipMemsetAsync(cursor, 0, CURSOR_BYTES, stream);
        p2_bucket<<<NB2, 1024, 0, stream>>>(events, n, cursor, bucket,
                                            oflist, ofcap, capg,
                                            curr_time, delta_t);
        p3_accum<<<2 * NGRP, 1024, 0, stream>>>(cursor, bucket, out, capg);
        p4_overflow<<<64, 256, 0, stream>>>(cursor, oflist, ofcap, out);
    } else {
        hipMemsetAsync(out, 0, (size_t)out_size * sizeof(float), stream);
        const int block = 256;
        const int grid  = (n + block - 1) / block;
        voxel_scatter_kernel<<<grid, block, 0, stream>>>(events, out, n,
                                                         curr_time, delta_t,
                                                         width, height);
    }
}